// Round 4
// baseline (44.232 us; speedup 1.0000x reference)
//
#include <hip/hip_runtime.h>
#include <math.h>

// Problem constants (from reference):
constexpr int Bn = 1024;
constexpr int S  = 512;
constexpr int H  = 768;
constexpr int D1 = 128;
constexpr int HV = H / 4;     // 192 float4 per feature row
constexpr int PSPLIT = 4;     // row-parity split of each span

// ws layout (floats):
//   cls [Bn][768]        — CLS features
//   gp  [4][Bn][768]     — span-mean partials (row s%4==p), pre-scaled by 1/len

// Kernel 1: ragged span mean-pool, 4 blocks/example (stride-4 rows).
// 4096 blocks x 192 thr = 12 blocks/CU; 4 independent loads in flight/wave.
__global__ __launch_bounds__(192) void pool_partial(
    const float* __restrict__ feat, const int* __restrict__ start,
    const int* __restrict__ endp, float* __restrict__ cls,
    float* __restrict__ gp) {
  const int b = blockIdx.x >> 2;
  const int p = blockIdx.x & 3;
  const int t = threadIdx.x;  // one float4 column
  const float4* base = reinterpret_cast<const float4*>(feat) + (size_t)b * (S * HV);

  if (p == 0) {
    reinterpret_cast<float4*>(cls)[(size_t)b * HV + t] = base[t];  // CLS row
  }

  const int s0 = start[b];
  const int s1 = endp[b];
  float4 a0{0,0,0,0}, a1{0,0,0,0}, a2{0,0,0,0}, a3{0,0,0,0};
  int s = s0 + p;
  for (; s + 12 < s1; s += 16) {
    float4 v0 = base[(size_t)(s +  0) * HV + t];
    float4 v1 = base[(size_t)(s +  4) * HV + t];
    float4 v2 = base[(size_t)(s +  8) * HV + t];
    float4 v3 = base[(size_t)(s + 12) * HV + t];
    a0.x += v0.x; a0.y += v0.y; a0.z += v0.z; a0.w += v0.w;
    a1.x += v1.x; a1.y += v1.y; a1.z += v1.z; a1.w += v1.w;
    a2.x += v2.x; a2.y += v2.y; a2.z += v2.z; a2.w += v2.w;
    a3.x += v3.x; a3.y += v3.y; a3.z += v3.z; a3.w += v3.w;
  }
  for (; s < s1; s += 4) {
    float4 v = base[(size_t)s * HV + t];
    a0.x += v.x; a0.y += v.y; a0.z += v.z; a0.w += v.w;
  }
  const float inv = 1.0f / (float)(s1 - s0);
  float4 r;
  r.x = ((a0.x + a1.x) + (a2.x + a3.x)) * inv;
  r.y = ((a0.y + a1.y) + (a2.y + a3.y)) * inv;
  r.z = ((a0.z + a1.z) + (a2.z + a3.z)) * inv;
  r.w = ((a0.w + a1.w) + (a2.w + a3.w)) * inv;
  reinterpret_cast<float4*>(gp)[((size_t)p * Bn + b) * HV + t] = r;
}

// Kernel 2: full head per block. 4 examples/block, 256 blocks x 512 thr.
// Thread = (ksl 0..31, seg 0..15): 4ex x 4k micro-tile over a 96-row d-seg.
// g from LDS as b128 reused across 4 d's; W1 from L2, coalesced b128.
// In-block seg-reduce + relu + W2 dot + sigmoid -> out. No finalize kernel.
__global__ __launch_bounds__(512) void head_full(
    const float* __restrict__ cls, const float* __restrict__ gp,
    const float* __restrict__ W1, const float* __restrict__ b1,
    const float* __restrict__ W2, const float* __restrict__ b2,
    float* __restrict__ out) {
  __shared__ float g[4][2 * H];       // 24 KB
  __shared__ float red[16][4][D1];    // 32 KB
  __shared__ float wsum[8];

  const int t = threadIdx.x;
  const int e0 = blockIdx.x * 4;

  // Stage g = [cls | sum of 4 scaled partials], 1536 float4 total
  const float4* cls4 = reinterpret_cast<const float4*>(cls);
  const float4* gp4  = reinterpret_cast<const float4*>(gp);
  for (int i = t; i < 4 * 2 * HV; i += 512) {
    const int e = i / (2 * HV);       // 0..3
    const int j = i % (2 * HV);       // float4 index within 1536 floats
    float4 v;
    if (j < HV) {
      v = cls4[(size_t)(e0 + e) * HV + j];
    } else {
      const int jj = j - HV;
      float4 u0 = gp4[((size_t)0 * Bn + e0 + e) * HV + jj];
      float4 u1 = gp4[((size_t)1 * Bn + e0 + e) * HV + jj];
      float4 u2 = gp4[((size_t)2 * Bn + e0 + e) * HV + jj];
      float4 u3 = gp4[((size_t)3 * Bn + e0 + e) * HV + jj];
      v.x = (u0.x + u1.x) + (u2.x + u3.x);
      v.y = (u0.y + u1.y) + (u2.y + u3.y);
      v.z = (u0.z + u1.z) + (u2.z + u3.z);
      v.w = (u0.w + u1.w) + (u2.w + u3.w);
    }
    reinterpret_cast<float4*>(&g[e][0])[j] = v;
  }
  __syncthreads();

  const int ksl = t & 31;             // k0 = ksl*4
  const int seg = t >> 5;             // d-seg 0..15, 96 rows each
  const int d0 = seg * 96;
  const float4* Wv = reinterpret_cast<const float4*>(W1 + (size_t)d0 * D1) + ksl;

  float acc[4][4];
  #pragma unroll
  for (int e = 0; e < 4; ++e)
    #pragma unroll
    for (int j = 0; j < 4; ++j) acc[e][j] = 0.f;

  #pragma unroll 4
  for (int dd = 0; dd < 96; dd += 4) {
    // W1 rows dd..dd+3, 4 k's per lane: coalesced 16B/lane from L2
    float4 w0 = Wv[(size_t)(dd + 0) * 32];
    float4 w1 = Wv[(size_t)(dd + 1) * 32];
    float4 w2 = Wv[(size_t)(dd + 2) * 32];
    float4 w3 = Wv[(size_t)(dd + 3) * 32];
    // g[e][d0+dd .. +4): one b128 per example, reused across 4 d's
    float4 g0 = *reinterpret_cast<const float4*>(&g[0][d0 + dd]);
    float4 g1 = *reinterpret_cast<const float4*>(&g[1][d0 + dd]);
    float4 g2 = *reinterpret_cast<const float4*>(&g[2][d0 + dd]);
    float4 g3 = *reinterpret_cast<const float4*>(&g[3][d0 + dd]);
    #define ACCUM(e, gv)                                            \
      acc[e][0] += gv.x * w0.x + gv.y * w1.x + gv.z * w2.x + gv.w * w3.x; \
      acc[e][1] += gv.x * w0.y + gv.y * w1.y + gv.z * w2.y + gv.w * w3.y; \
      acc[e][2] += gv.x * w0.z + gv.y * w1.z + gv.z * w2.z + gv.w * w3.z; \
      acc[e][3] += gv.x * w0.w + gv.y * w1.w + gv.z * w2.w + gv.w * w3.w;
    ACCUM(0, g0) ACCUM(1, g1) ACCUM(2, g2) ACCUM(3, g3)
    #undef ACCUM
  }

  // Dump partials: red[seg][e][ksl*4+j]
  #pragma unroll
  for (int e = 0; e < 4; ++e) {
    float4 v = make_float4(acc[e][0], acc[e][1], acc[e][2], acc[e][3]);
    *reinterpret_cast<float4*>(&red[seg][e][ksl * 4]) = v;
  }
  __syncthreads();

  // Combine 16 segs: thread = (e = t>>7, k = t&127)
  {
    const int e = t >> 7;
    const int k = t & (D1 - 1);
    float h = b1[k];
    #pragma unroll
    for (int s = 0; s < 16; ++s) h += red[s][e][k];
    h = fmaxf(h, 0.f);
    float v = h * W2[k];
    #pragma unroll
    for (int off = 32; off > 0; off >>= 1) v += __shfl_down(v, off);
    if ((t & 63) == 0) wsum[t >> 6] = v;
  }
  __syncthreads();

  if (t < 4) {
    float s = wsum[2 * t] + wsum[2 * t + 1] + b2[0];
    out[e0 + t] = 1.0f / (1.0f + expf(-s));
  }
}

extern "C" void kernel_launch(void* const* d_in, const int* in_sizes, int n_in,
                              void* d_out, int out_size, void* d_ws, size_t ws_size,
                              hipStream_t stream) {
  const float* feat = (const float*)d_in[0];   // [B,S,H] fp32
  const int* start  = (const int*)d_in[1];     // [B]
  const int* endp   = (const int*)d_in[2];     // [B]
  const float* W1   = (const float*)d_in[3];   // [2H,D1]
  const float* b1   = (const float*)d_in[4];   // [D1]
  const float* W2   = (const float*)d_in[5];   // [D1,1]
  const float* b2   = (const float*)d_in[6];   // [1]
  float* out = (float*)d_out;                  // [B]

  float* wsf = (float*)d_ws;
  float* cls = wsf;                            // [Bn][768]
  float* gp  = cls + (size_t)Bn * H;           // [4][Bn][768]

  hipLaunchKernelGGL(pool_partial, dim3(Bn * PSPLIT), dim3(192), 0, stream,
                     feat, start, endp, cls, gp);
  hipLaunchKernelGGL(head_full, dim3(Bn / 4), dim3(512), 0, stream,
                     cls, gp, W1, b1, W2, b2, out);
}